// Round 2
// baseline (343.475 us; speedup 1.0000x reference)
//
#include <hip/hip_runtime.h>
#include <hip/hip_bf16.h>

#define NT 1024     // tokens (B*S)
#define HD 1024     // hidden
#define ED 1024     // expert inner dim
#define F2D 2048    // 2*E (interleaved gate/up)
#define NEXPERT 16
#define GROWS 2304  // compacted rows (2048) + tile slack (gemm2 reads up to base+255 <= 2303)
#define ALPHA_C 1.702f
#define LIMIT_C 7.0f

typedef float f32x4 __attribute__((ext_vector_type(4)));
typedef float fv4 __attribute__((ext_vector_type(4)));
typedef short short8 __attribute__((ext_vector_type(8)));
typedef unsigned int u32x4 __attribute__((ext_vector_type(4)));

__device__ __forceinline__ unsigned short f2bf(float x) {
  union { float f; unsigned int u; } v; v.f = x;
  unsigned int r = v.u + 0x7FFFu + ((v.u >> 16) & 1u);
  return (unsigned short)(r >> 16);
}
__device__ __forceinline__ unsigned int pk2(float lo, float hi) {
  return (unsigned int)f2bf(lo) | ((unsigned int)f2bf(hi) << 16);
}
// non-temporal float4 load (weights: stream, don't cache)
__device__ __forceinline__ fv4 ldnt4(const float* p) {
  return __builtin_nontemporal_load((const fv4*)p);
}
// async global->LDS, 16B per lane; LDS dest = wave-uniform base + lane*16
__device__ __forceinline__ void async16(const void* g, void* l) {
  __builtin_amdgcn_global_load_lds((const __attribute__((address_space(1))) void*)g,
                                   (__attribute__((address_space(3))) void*)l, 16, 0, 0);
}

// ---------------- router: fp32 logits, top-2, softmax; x->bf16 ----------------
__global__ __launch_bounds__(64) void k_router(const float* __restrict__ x,
                                               const float* __restrict__ Wg,
                                               const float* __restrict__ bg,
                                               int* __restrict__ e01,
                                               float* __restrict__ w0f,
                                               float* __restrict__ w1f,
                                               unsigned short* __restrict__ Xbf) {
  const int t = blockIdx.x;
  const int l = threadIdx.x;
  const float4* x4 = (const float4*)(x + (size_t)t * HD);
  for (int i = 0; i < 4; ++i) {
    const int idx = l + 64 * i;
    float4 v = x4[idx];
    unsigned int a = pk2(v.x, v.y);
    unsigned int b = pk2(v.z, v.w);
    unsigned int* dst = (unsigned int*)(Xbf + (size_t)t * HD + idx * 4);
    dst[0] = a; dst[1] = b;
  }
  const int e = l & 15, qq = l >> 4;
  const float4* wg4 = (const float4*)(Wg + (size_t)e * HD);
  float s0a = 0.f, s1a = 0.f;
#pragma unroll 8
  for (int j = 0; j < 32; ++j) {
    const int i0 = qq + 8 * j;
    const int i1 = i0 + 4;
    float4 a0 = x4[i0], b0 = wg4[i0];
    float4 a1 = x4[i1], b1 = wg4[i1];
    s0a += a0.x * b0.x + a0.y * b0.y + a0.z * b0.z + a0.w * b0.w;
    s1a += a1.x * b1.x + a1.y * b1.y + a1.z * b1.z + a1.w * b1.w;
  }
  float s = s0a + s1a;
  s += __shfl_xor(s, 16);
  s += __shfl_xor(s, 32);
  const float logit = s + bg[e];  // valid in lanes 0..15
  float v0 = -1e30f, v1 = -1e30f; int i0 = 0, i1 = 0;
  for (int k = 0; k < 16; ++k) {
    float lv = __shfl(logit, k);
    if (lv > v0) { v1 = v0; i1 = i0; v0 = lv; i0 = k; }
    else if (lv > v1) { v1 = lv; i1 = k; }
  }
  const float w0 = 1.f / (1.f + __expf(v1 - v0));
  const float w1 = 1.f - w0;
  if (l == 0) {
    e01[t] = i0 | (i1 << 8);
    w0f[t] = w0;
    w1f[t] = w1;
  }
}

// ---------------- scan: counts, offsets, placement + slot indices (one block) ----------------
__global__ __launch_bounds__(1024) void k_scan(const int* __restrict__ e01,
                                               int* __restrict__ cnt,
                                               int* __restrict__ off,
                                               int* __restrict__ gtok,
                                               int* __restrict__ sl01) {
  __shared__ int scnt[NEXPERT];
  __shared__ int soff[NEXPERT];
  __shared__ int scur[NEXPERT];
  const int t = threadIdx.x;
  if (t < NEXPERT) { scnt[t] = 0; scur[t] = 0; }
  __syncthreads();
  const int p = e01[t];
  const int e0 = p & 255, e1 = p >> 8;
  atomicAdd(&scnt[e0], 1);
  atomicAdd(&scnt[e1], 1);
  __syncthreads();
  if (t == 0) {
    int a = 0;
    for (int e = 0; e < NEXPERT; ++e) { soff[e] = a; off[e] = a; cnt[e] = scnt[e]; a += scnt[e]; }
  }
  __syncthreads();
  int s0 = atomicAdd(&scur[e0], 1);
  const int g0 = soff[e0] + s0;
  gtok[g0] = t;
  int s1 = atomicAdd(&scur[e1], 1);
  const int g1 = soff[e1] + s1;
  gtok[g1] = t;
  sl01[t] = g0 | (g1 << 16);
}

// ---------------- GEMM1: block 256M x 128N, 512 thr (8 waves 4mx2n), BK=32, dbuf, weights read ONCE ----------------
// grid (16 ntiles, 2 mtiles, 16 experts); Wgu[e] is [K=1024][N=2048]
#define BSTG1 132   // Blds row stride in dwords (128 + 4 pad)
__global__ __launch_bounds__(512, 1) void k_gemm1(const unsigned short* __restrict__ Xbf,
                                                  const float* __restrict__ Wgu,
                                                  const float* __restrict__ bgu,
                                                  const int* __restrict__ cnt,
                                                  const int* __restrict__ off,
                                                  const int* __restrict__ gtok,
                                                  unsigned short* __restrict__ Gact) {
  const int e = blockIdx.z;
  const int Ne = cnt[e];
  const int mtile = blockIdx.y;
  if (mtile * 256 >= Ne) return;
  const int ntile = blockIdx.x;
  const int tid = threadIdx.x;          // 0..511
  const int lane = tid & 63;
  const int wv = tid >> 6;              // 0..7
  const int wm = wv >> 1;               // 0..3  (M 64-slice)
  const int wn = wv & 1;                // 0..1  (N 64-slice)
  const int q = lane >> 4;
  const int fr = lane & 15;
  const int base = off[e] + mtile * 256;

  __shared__ unsigned short Alds[2][256 * 32];   // [buf][row*32 + k]  (64B rows)  32 KB
  __shared__ unsigned int Blds[2][16 * BSTG1];   // [buf][kpair*BSTG1 + n]        ~17 KB

  // A staging: wave wv stages rows wv*32 + (lane>>2) and +16; chunk = lane&3
  const int ar0 = wv * 32 + (lane >> 2);
  const int ar1 = ar0 + 16;
  const int ags0 = base + (((mtile * 256 + ar0) < Ne) ? ar0 : 0);
  const int ags1 = base + (((mtile * 256 + ar1) < Ne) ? ar1 : 0);
  const unsigned short* agp0 = Xbf + (size_t)gtok[ags0] * HD + (lane & 3) * 8;
  const unsigned short* agp1 = Xbf + (size_t)gtok[ags1] * HD + (lane & 3) * 8;
  const int aofs = wv * 1024;  // shorts: 32 rows * 32 shorts

  // B staging: thread -> kpair p2 = tid>>5 (0..15), colgrp bc = tid&31 (4 cols each)
  const int p2 = tid >> 5;
  const int bc = tid & 31;
  const float* Wb = Wgu + (size_t)e * HD * F2D + (size_t)(2 * p2) * F2D + ntile * 128 + bc * 4;

  f32x4 acc[4][4] = {};
  fv4 b0, b1;

  // prologue: stage tile 0
  b0 = ldnt4(Wb);
  b1 = ldnt4(Wb + F2D);
  async16(agp0, Alds[0] + aofs);
  async16(agp1, Alds[0] + aofs + 512);
  {
    u32x4 pkv;
    pkv[0] = pk2(b0[0], b1[0]); pkv[1] = pk2(b0[1], b1[1]);
    pkv[2] = pk2(b0[2], b1[2]); pkv[3] = pk2(b0[3], b1[3]);
    *(u32x4*)(Blds[0] + p2 * BSTG1 + bc * 4) = pkv;
  }
  __syncthreads();

  for (int ks = 0; ks < 32; ++ks) {
    const int cur = ks & 1, nxt = cur ^ 1;
    const bool more = (ks + 1) < 32;
    if (more) {
      const float* bp = Wb + (size_t)(ks + 1) * 32 * F2D;
      b0 = ldnt4(bp);
      b1 = ldnt4(bp + F2D);
      async16(agp0 + (ks + 1) * 32, Alds[nxt] + aofs);
      async16(agp1 + (ks + 1) * 32, Alds[nxt] + aofs + 512);
    }
    short8 af[4], bfr[4];
#pragma unroll
    for (int mi = 0; mi < 4; ++mi)
      af[mi] = *(const short8*)(Alds[cur] + (wm * 64 + mi * 16 + fr) * 32 + q * 8);
#pragma unroll
    for (int ni = 0; ni < 4; ++ni) {
      const unsigned int* p = Blds[cur] + (q * 4) * BSTG1 + wn * 64 + ni * 16 + fr;
      union { unsigned int u[4]; short8 s; } uu;
      uu.u[0] = p[0]; uu.u[1] = p[BSTG1]; uu.u[2] = p[2 * BSTG1]; uu.u[3] = p[3 * BSTG1];
      bfr[ni] = uu.s;
    }
#pragma unroll
    for (int mi = 0; mi < 4; ++mi)
#pragma unroll
      for (int ni = 0; ni < 4; ++ni)
        acc[mi][ni] = __builtin_amdgcn_mfma_f32_16x16x32_bf16(af[mi], bfr[ni], acc[mi][ni], 0, 0, 0);
    if (more) {
      u32x4 pkv;
      pkv[0] = pk2(b0[0], b1[0]); pkv[1] = pk2(b0[1], b1[1]);
      pkv[2] = pk2(b0[2], b1[2]); pkv[3] = pk2(b0[3], b1[3]);
      *(u32x4*)(Blds[nxt] + p2 * BSTG1 + bc * 4) = pkv;
    }
    __syncthreads();
  }

  // epilogue: +bgu, de-interleave gate/up via lane-pair shuffle, activation, store bf16
  const float* bguE = bgu + (size_t)e * F2D + ntile * 128;
#pragma unroll
  for (int mi = 0; mi < 4; ++mi) {
#pragma unroll
    for (int ni = 0; ni < 4; ++ni) {
      const int coll = wn * 64 + ni * 16 + fr;
      const float bias = bguE[coll];
#pragma unroll
      for (int r = 0; r < 4; ++r) {
        const int srow = wm * 64 + mi * 16 + q * 4 + r;
        float v = acc[mi][ni][r] + bias;
        float pv = __shfl_xor(v, 1);
        float gate = (lane & 1) ? pv : v;   // even f2-cols are gate, odd are up
        float up   = (lane & 1) ? v : pv;
        gate = fminf(gate, LIMIT_C);
        up = fminf(fmaxf(up, -LIMIT_C), LIMIT_C);
        float glu = gate / (1.f + __expf(-ALPHA_C * gate));
        float val = (up + 1.f) * glu;
        if (!(lane & 1) && (mtile * 256 + srow) < Ne)
          Gact[(size_t)(base + srow) * ED + ((ntile * 128 + coll) >> 1)] = f2bf(val);
      }
    }
  }
}

// ---------------- GEMM2: block 256M x 64N, 256 thr (4 waves, M-split), BK=32, dbuf, Wd read ONCE ----------------
// grid (16 ntiles, 2 mtiles, 16 experts); Wd[e] is [K=1024][N=1024]
// stores RAW per-slot rows to Oe (no weight, no atomics); combine pass applies weights+bd
#define BSTG2 68   // Blds row stride in dwords (64 + 4 pad)
__global__ __launch_bounds__(256, 2) void k_gemm2(const unsigned short* __restrict__ Gact,
                                                  const float* __restrict__ Wd,
                                                  const int* __restrict__ cnt,
                                                  const int* __restrict__ off,
                                                  float* __restrict__ Oe) {
  const int e = blockIdx.z;
  const int Ne = cnt[e];
  const int mtile = blockIdx.y;
  if (mtile * 256 >= Ne) return;
  const int ntile = blockIdx.x;
  const int tid = threadIdx.x;          // 0..255
  const int lane = tid & 63;
  const int wv = tid >> 6;              // 0..3 (M 64-slice; N full 64)
  const int q = lane >> 4;
  const int fr = lane & 15;
  const int base = off[e] + mtile * 256;

  __shared__ unsigned short Alds[2][256 * 32];   // 32 KB
  __shared__ unsigned int Blds[2][16 * BSTG2];   // ~8.7 KB

  // A staging: wave wv stages rows wv*64 + j*16 + (lane>>2), j=0..3 (rows base+0..255 < GROWS: safe)
  const int arb = wv * 64 + (lane >> 2);
  const unsigned short* agp = Gact + (size_t)(base + arb) * ED + (lane & 3) * 8;
  const int aofs = wv * 2048;  // shorts: 64 rows * 32 shorts

  // B staging: thread -> kpair p2 = tid>>4 (0..15), colgrp bc = tid&15 (4 cols each)
  const int p2 = tid >> 4;
  const int bc = tid & 15;
  const float* Wb = Wd + (size_t)e * ED * HD + (size_t)(2 * p2) * HD + ntile * 64 + bc * 4;

  f32x4 acc[4][4] = {};
  fv4 b0, b1;

  b0 = ldnt4(Wb);
  b1 = ldnt4(Wb + HD);
#pragma unroll
  for (int j = 0; j < 4; ++j)
    async16(agp + (size_t)j * 16 * ED, Alds[0] + aofs + j * 512);
  {
    u32x4 pkv;
    pkv[0] = pk2(b0[0], b1[0]); pkv[1] = pk2(b0[1], b1[1]);
    pkv[2] = pk2(b0[2], b1[2]); pkv[3] = pk2(b0[3], b1[3]);
    *(u32x4*)(Blds[0] + p2 * BSTG2 + bc * 4) = pkv;
  }
  __syncthreads();

  for (int ks = 0; ks < 32; ++ks) {
    const int cur = ks & 1, nxt = cur ^ 1;
    const bool more = (ks + 1) < 32;
    if (more) {
      const float* bp = Wb + (size_t)(ks + 1) * 32 * HD;
      b0 = ldnt4(bp);
      b1 = ldnt4(bp + HD);
#pragma unroll
      for (int j = 0; j < 4; ++j)
        async16(agp + (ks + 1) * 32 + (size_t)j * 16 * ED, Alds[nxt] + aofs + j * 512);
    }
    short8 af[4], bfr[4];
#pragma unroll
    for (int mi = 0; mi < 4; ++mi)
      af[mi] = *(const short8*)(Alds[cur] + (wv * 64 + mi * 16 + fr) * 32 + q * 8);
#pragma unroll
    for (int ni = 0; ni < 4; ++ni) {
      const unsigned int* p = Blds[cur] + (q * 4) * BSTG2 + ni * 16 + fr;
      union { unsigned int u[4]; short8 s; } uu;
      uu.u[0] = p[0]; uu.u[1] = p[BSTG2]; uu.u[2] = p[2 * BSTG2]; uu.u[3] = p[3 * BSTG2];
      bfr[ni] = uu.s;
    }
#pragma unroll
    for (int mi = 0; mi < 4; ++mi)
#pragma unroll
      for (int ni = 0; ni < 4; ++ni)
        acc[mi][ni] = __builtin_amdgcn_mfma_f32_16x16x32_bf16(af[mi], bfr[ni], acc[mi][ni], 0, 0, 0);
    if (more) {
      u32x4 pkv;
      pkv[0] = pk2(b0[0], b1[0]); pkv[1] = pk2(b0[1], b1[1]);
      pkv[2] = pk2(b0[2], b1[2]); pkv[3] = pk2(b0[3], b1[3]);
      *(u32x4*)(Blds[nxt] + p2 * BSTG2 + bc * 4) = pkv;
    }
    __syncthreads();
  }

  // epilogue: raw coalesced stores to per-slot rows (weights + bd applied in combine)
#pragma unroll
  for (int mi = 0; mi < 4; ++mi) {
#pragma unroll
    for (int r = 0; r < 4; ++r) {
      const int srow = wv * 64 + mi * 16 + q * 4 + r;
      if ((mtile * 256 + srow) < Ne) {
        float* op = Oe + (size_t)(base + srow) * HD + ntile * 64;
#pragma unroll
        for (int ni = 0; ni < 4; ++ni)
          op[ni * 16 + fr] = acc[mi][ni][r];
      }
    }
  }
}

// ---------------- combine: out[t] = w0*(Oe[s0]+bd[e0]) + w1*(Oe[s1]+bd[e1]) ----------------
__global__ __launch_bounds__(256) void k_combine(const float* __restrict__ Oe,
                                                 const float* __restrict__ bd,
                                                 const int* __restrict__ e01,
                                                 const int* __restrict__ sl01,
                                                 const float* __restrict__ w0f,
                                                 const float* __restrict__ w1f,
                                                 float* __restrict__ out) {
  const int t = blockIdx.x;
  const int i = threadIdx.x;  // 256 threads, one float4 each
  const int p = e01[t];
  const int e0 = p & 255, e1 = p >> 8;
  const int sl = sl01[t];
  const int s0 = sl & 0xFFFF, s1 = (sl >> 16) & 0xFFFF;
  const float w0 = w0f[t], w1 = w1f[t];
  float4 a = ((const float4*)(Oe + (size_t)s0 * HD))[i];
  float4 b = ((const float4*)(Oe + (size_t)s1 * HD))[i];
  float4 c = ((const float4*)(bd + (size_t)e0 * HD))[i];
  float4 d = ((const float4*)(bd + (size_t)e1 * HD))[i];
  float4 r;
  r.x = w0 * (a.x + c.x) + w1 * (b.x + d.x);
  r.y = w0 * (a.y + c.y) + w1 * (b.y + d.y);
  r.z = w0 * (a.z + c.z) + w1 * (b.z + d.z);
  r.w = w0 * (a.w + c.w) + w1 * (b.w + d.w);
  ((float4*)(out + (size_t)t * HD))[i] = r;
}

extern "C" void kernel_launch(void* const* d_in, const int* in_sizes, int n_in,
                              void* d_out, int out_size, void* d_ws, size_t ws_size,
                              hipStream_t stream) {
  const float* x   = (const float*)d_in[0];
  const float* Wg  = (const float*)d_in[1];
  const float* bg  = (const float*)d_in[2];
  const float* Wgu = (const float*)d_in[3];
  const float* bgu = (const float*)d_in[4];
  const float* Wd  = (const float*)d_in[5];
  const float* bd  = (const float*)d_in[6];
  float* out = (float*)d_out;

  int* cnt = (int*)d_ws;                    // 16
  int* off = cnt + 16;                      // 16
  int* e01 = off + 16;                      // NT
  int* sl01 = e01 + NT;                     // NT
  float* w0f = (float*)(sl01 + NT);         // NT
  float* w1f = w0f + NT;                    // NT
  int* gtok = (int*)(w1f + NT);             // GROWS
  float* Oe = (float*)(gtok + GROWS);       // GROWS*HD fp32 (slot-major expert outputs)
  unsigned short* Xbf = (unsigned short*)(Oe + (size_t)GROWS * HD);   // NT*HD bf16
  unsigned short* Gact = Xbf + (size_t)NT * HD;                       // GROWS*ED bf16

  k_router<<<NT, 64, 0, stream>>>(x, Wg, bg, e01, w0f, w1f, Xbf);
  k_scan<<<1, NT, 0, stream>>>(e01, cnt, off, gtok, sl01);
  k_gemm1<<<dim3(16, 2, NEXPERT), 512, 0, stream>>>(Xbf, Wgu, bgu, cnt, off, gtok, Gact);
  k_gemm2<<<dim3(16, 2, NEXPERT), 256, 0, stream>>>(Gact, Wd, cnt, off, Oe);
  k_combine<<<NT, 256, 0, stream>>>(Oe, bd, e01, sl01, w0f, w1f, out);
}

// Round 3
// 332.367 us; speedup vs baseline: 1.0334x; 1.0334x over previous
//
#include <hip/hip_runtime.h>
#include <hip/hip_bf16.h>

#define NT 1024     // tokens (B*S)
#define HD 1024     // hidden
#define ED 1024     // expert inner dim
#define F2D 2048    // 2*E (interleaved gate/up)
#define NEXPERT 16
#define GROWS 2304  // compacted rows (2048) + tile slack (gemm2 reads up to base+255 <= 2303)
#define ALPHA_C 1.702f
#define LIMIT_C 7.0f

typedef float f32x4 __attribute__((ext_vector_type(4)));
typedef float fv4 __attribute__((ext_vector_type(4)));
typedef short short8 __attribute__((ext_vector_type(8)));
typedef unsigned int u32x4 __attribute__((ext_vector_type(4)));

__device__ __forceinline__ unsigned short f2bf(float x) {
  union { float f; unsigned int u; } v; v.f = x;
  unsigned int r = v.u + 0x7FFFu + ((v.u >> 16) & 1u);
  return (unsigned short)(r >> 16);
}
__device__ __forceinline__ unsigned int pk2(float lo, float hi) {
  return (unsigned int)f2bf(lo) | ((unsigned int)f2bf(hi) << 16);
}
// non-temporal float4 load (weights: stream, don't cache)
__device__ __forceinline__ fv4 ldnt4(const float* p) {
  return __builtin_nontemporal_load((const fv4*)p);
}
// async global->LDS, 16B per lane; LDS dest = wave-uniform base + lane*16
__device__ __forceinline__ void async16(const void* g, void* l) {
  __builtin_amdgcn_global_load_lds((const __attribute__((address_space(1))) void*)g,
                                   (__attribute__((address_space(3))) void*)l, 16, 0, 0);
}

// ---------------- router: fp32 logits, top-2, softmax; x->bf16; out = w0*bd[e0]+w1*bd[e1] ----------------
__global__ __launch_bounds__(64) void k_router(const float* __restrict__ x,
                                               const float* __restrict__ Wg,
                                               const float* __restrict__ bg,
                                               const float* __restrict__ bd,
                                               int* __restrict__ e01,
                                               float* __restrict__ w0f,
                                               float* __restrict__ w1f,
                                               unsigned short* __restrict__ Xbf,
                                               float* __restrict__ out) {
  const int t = blockIdx.x;
  const int l = threadIdx.x;
  const float4* x4 = (const float4*)(x + (size_t)t * HD);
  for (int i = 0; i < 4; ++i) {
    const int idx = l + 64 * i;
    float4 v = x4[idx];
    unsigned int a = pk2(v.x, v.y);
    unsigned int b = pk2(v.z, v.w);
    unsigned int* dst = (unsigned int*)(Xbf + (size_t)t * HD + idx * 4);
    dst[0] = a; dst[1] = b;
  }
  const int e = l & 15, qq = l >> 4;
  const float4* wg4 = (const float4*)(Wg + (size_t)e * HD);
  float s0a = 0.f, s1a = 0.f;
#pragma unroll 8
  for (int j = 0; j < 32; ++j) {
    const int i0 = qq + 8 * j;
    const int i1 = i0 + 4;
    float4 a0 = x4[i0], b0 = wg4[i0];
    float4 a1 = x4[i1], b1 = wg4[i1];
    s0a += a0.x * b0.x + a0.y * b0.y + a0.z * b0.z + a0.w * b0.w;
    s1a += a1.x * b1.x + a1.y * b1.y + a1.z * b1.z + a1.w * b1.w;
  }
  float s = s0a + s1a;
  s += __shfl_xor(s, 16);
  s += __shfl_xor(s, 32);
  const float logit = s + bg[e];  // valid in lanes 0..15
  float v0 = -1e30f, v1 = -1e30f; int i0 = 0, i1 = 0;
  for (int k = 0; k < 16; ++k) {
    float lv = __shfl(logit, k);
    if (lv > v0) { v1 = v0; i1 = i0; v0 = lv; i0 = k; }
    else if (lv > v1) { v1 = lv; i1 = k; }
  }
  const float w0 = 1.f / (1.f + __expf(v1 - v0));
  const float w1 = 1.f - w0;
  if (l == 0) {
    e01[t] = i0 | (i1 << 8);
    w0f[t] = w0;
    w1f[t] = w1;
  }
  const float4* bd0 = (const float4*)(bd + (size_t)i0 * HD);
  const float4* bd1 = (const float4*)(bd + (size_t)i1 * HD);
  float4* o4 = (float4*)(out + (size_t)t * HD);
  for (int i = 0; i < 4; ++i) {
    const int idx = l + 64 * i;
    float4 a = bd0[idx], b = bd1[idx];
    float4 r;
    r.x = w0 * a.x + w1 * b.x;
    r.y = w0 * a.y + w1 * b.y;
    r.z = w0 * a.z + w1 * b.z;
    r.w = w0 * a.w + w1 * b.w;
    o4[idx] = r;
  }
}

// ---------------- scan: counts, offsets, placement (one block) ----------------
__global__ __launch_bounds__(1024) void k_scan(const int* __restrict__ e01,
                                               const float* __restrict__ w0f,
                                               const float* __restrict__ w1f,
                                               int* __restrict__ cnt,
                                               int* __restrict__ off,
                                               int* __restrict__ gtok,
                                               float* __restrict__ gwt) {
  __shared__ int scnt[NEXPERT];
  __shared__ int soff[NEXPERT];
  __shared__ int scur[NEXPERT];
  const int t = threadIdx.x;
  if (t < NEXPERT) { scnt[t] = 0; scur[t] = 0; }
  __syncthreads();
  const int p = e01[t];
  const int e0 = p & 255, e1 = p >> 8;
  atomicAdd(&scnt[e0], 1);
  atomicAdd(&scnt[e1], 1);
  __syncthreads();
  if (t == 0) {
    int a = 0;
    for (int e = 0; e < NEXPERT; ++e) { soff[e] = a; off[e] = a; cnt[e] = scnt[e]; a += scnt[e]; }
  }
  __syncthreads();
  int s0 = atomicAdd(&scur[e0], 1);
  gtok[soff[e0] + s0] = t; gwt[soff[e0] + s0] = w0f[t];
  int s1 = atomicAdd(&scur[e1], 1);
  gtok[soff[e1] + s1] = t; gwt[soff[e1] + s1] = w1f[t];
}

// ---------------- GEMM1: block 256M x 128N, 512 thr (8 waves 4mx2n), BK=32, dbuf, weights read ONCE ----------------
// grid (16 ntiles, 2 mtiles, 16 experts); Wgu[e] is [K=1024][N=2048]
#define BSTG1 132   // Blds row stride in dwords (128 + 4 pad)
__global__ __launch_bounds__(512, 1) void k_gemm1(const unsigned short* __restrict__ Xbf,
                                                  const float* __restrict__ Wgu,
                                                  const float* __restrict__ bgu,
                                                  const int* __restrict__ cnt,
                                                  const int* __restrict__ off,
                                                  const int* __restrict__ gtok,
                                                  unsigned short* __restrict__ Gact) {
  const int e = blockIdx.z;
  const int Ne = cnt[e];
  const int mtile = blockIdx.y;
  if (mtile * 256 >= Ne) return;
  const int ntile = blockIdx.x;
  const int tid = threadIdx.x;          // 0..511
  const int lane = tid & 63;
  const int wv = tid >> 6;              // 0..7
  const int wm = wv >> 1;               // 0..3  (M 64-slice)
  const int wn = wv & 1;                // 0..1  (N 64-slice)
  const int q = lane >> 4;
  const int fr = lane & 15;
  const int base = off[e] + mtile * 256;

  __shared__ unsigned short Alds[2][256 * 32];   // [buf][row*32 + k]  (64B rows)  32 KB
  __shared__ unsigned int Blds[2][16 * BSTG1];   // [buf][kpair*BSTG1 + n]        ~17 KB

  // A staging: wave wv stages rows wv*32 + (lane>>2) and +16; chunk = lane&3
  const int ar0 = wv * 32 + (lane >> 2);
  const int ar1 = ar0 + 16;
  const int ags0 = base + (((mtile * 256 + ar0) < Ne) ? ar0 : 0);
  const int ags1 = base + (((mtile * 256 + ar1) < Ne) ? ar1 : 0);
  const unsigned short* agp0 = Xbf + (size_t)gtok[ags0] * HD + (lane & 3) * 8;
  const unsigned short* agp1 = Xbf + (size_t)gtok[ags1] * HD + (lane & 3) * 8;
  const int aofs = wv * 1024;  // shorts: 32 rows * 32 shorts

  // B staging: thread -> kpair p2 = tid>>5 (0..15), colgrp bc = tid&31 (4 cols each)
  const int p2 = tid >> 5;
  const int bc = tid & 31;
  const float* Wb = Wgu + (size_t)e * HD * F2D + (size_t)(2 * p2) * F2D + ntile * 128 + bc * 4;

  f32x4 acc[4][4] = {};
  fv4 b0, b1;

  // prologue: stage tile 0
  b0 = ldnt4(Wb);
  b1 = ldnt4(Wb + F2D);
  async16(agp0, Alds[0] + aofs);
  async16(agp1, Alds[0] + aofs + 512);
  {
    u32x4 pkv;
    pkv[0] = pk2(b0[0], b1[0]); pkv[1] = pk2(b0[1], b1[1]);
    pkv[2] = pk2(b0[2], b1[2]); pkv[3] = pk2(b0[3], b1[3]);
    *(u32x4*)(Blds[0] + p2 * BSTG1 + bc * 4) = pkv;
  }
  __syncthreads();

  for (int ks = 0; ks < 32; ++ks) {
    const int cur = ks & 1, nxt = cur ^ 1;
    const bool more = (ks + 1) < 32;
    if (more) {
      const float* bp = Wb + (size_t)(ks + 1) * 32 * F2D;
      b0 = ldnt4(bp);
      b1 = ldnt4(bp + F2D);
      async16(agp0 + (ks + 1) * 32, Alds[nxt] + aofs);
      async16(agp1 + (ks + 1) * 32, Alds[nxt] + aofs + 512);
    }
    short8 af[4], bfr[4];
#pragma unroll
    for (int mi = 0; mi < 4; ++mi)
      af[mi] = *(const short8*)(Alds[cur] + (wm * 64 + mi * 16 + fr) * 32 + q * 8);
#pragma unroll
    for (int ni = 0; ni < 4; ++ni) {
      const unsigned int* p = Blds[cur] + (q * 4) * BSTG1 + wn * 64 + ni * 16 + fr;
      union { unsigned int u[4]; short8 s; } uu;
      uu.u[0] = p[0]; uu.u[1] = p[BSTG1]; uu.u[2] = p[2 * BSTG1]; uu.u[3] = p[3 * BSTG1];
      bfr[ni] = uu.s;
    }
#pragma unroll
    for (int mi = 0; mi < 4; ++mi)
#pragma unroll
      for (int ni = 0; ni < 4; ++ni)
        acc[mi][ni] = __builtin_amdgcn_mfma_f32_16x16x32_bf16(af[mi], bfr[ni], acc[mi][ni], 0, 0, 0);
    if (more) {
      u32x4 pkv;
      pkv[0] = pk2(b0[0], b1[0]); pkv[1] = pk2(b0[1], b1[1]);
      pkv[2] = pk2(b0[2], b1[2]); pkv[3] = pk2(b0[3], b1[3]);
      *(u32x4*)(Blds[nxt] + p2 * BSTG1 + bc * 4) = pkv;
    }
    __syncthreads();
  }

  // epilogue: +bgu, de-interleave gate/up via lane-pair shuffle, activation, store bf16
  const float* bguE = bgu + (size_t)e * F2D + ntile * 128;
#pragma unroll
  for (int mi = 0; mi < 4; ++mi) {
#pragma unroll
    for (int ni = 0; ni < 4; ++ni) {
      const int coll = wn * 64 + ni * 16 + fr;
      const float bias = bguE[coll];
#pragma unroll
      for (int r = 0; r < 4; ++r) {
        const int srow = wm * 64 + mi * 16 + q * 4 + r;
        float v = acc[mi][ni][r] + bias;
        float pv = __shfl_xor(v, 1);
        float gate = (lane & 1) ? pv : v;   // even f2-cols are gate, odd are up
        float up   = (lane & 1) ? v : pv;
        gate = fminf(gate, LIMIT_C);
        up = fminf(fmaxf(up, -LIMIT_C), LIMIT_C);
        float glu = gate / (1.f + __expf(-ALPHA_C * gate));
        float val = (up + 1.f) * glu;
        if (!(lane & 1) && (mtile * 256 + srow) < Ne)
          Gact[(size_t)(base + srow) * ED + ((ntile * 128 + coll) >> 1)] = f2bf(val);
      }
    }
  }
}

// ---------------- GEMM2: block 256M x 64N, 512 thr (8 waves, M-split 32 rows/wave), BK=32, dbuf ----------------
// grid (16 ntiles, 2 mtiles, 16 experts); Wd[e] is [K=1024][N=1024]; atomic epilogue (atomics measured cheap)
#define BSTG2 68   // Blds row stride in dwords (64 + 4 pad)
__global__ __launch_bounds__(512, 2) void k_gemm2(const unsigned short* __restrict__ Gact,
                                                  const float* __restrict__ Wd,
                                                  const int* __restrict__ cnt,
                                                  const int* __restrict__ off,
                                                  const int* __restrict__ gtok,
                                                  const float* __restrict__ gwt,
                                                  float* __restrict__ out) {
  const int e = blockIdx.z;
  const int Ne = cnt[e];
  const int mtile = blockIdx.y;
  if (mtile * 256 >= Ne) return;
  const int ntile = blockIdx.x;
  const int tid = threadIdx.x;          // 0..511
  const int lane = tid & 63;
  const int wv = tid >> 6;              // 0..7 (M 32-slice; N full 64)
  const int q = lane >> 4;
  const int fr = lane & 15;
  const int base = off[e] + mtile * 256;

  __shared__ unsigned short Alds[2][256 * 32];   // 32 KB
  __shared__ unsigned int Blds[2][16 * BSTG2];   // ~8.7 KB

  // A staging: wave wv stages rows wv*32 + (lane>>2) and +16; chunk = lane&3
  // rows base+0..255 < GROWS: safe
  const int ar0 = wv * 32 + (lane >> 2);
  const unsigned short* agp0 = Gact + (size_t)(base + ar0) * ED + (lane & 3) * 8;
  const unsigned short* agp1 = agp0 + (size_t)16 * ED;
  const int aofs = wv * 1024;  // shorts: 32 rows * 32 shorts

  // B staging (waves 0..3 only): thread -> kpair p2 = tid>>4 (0..15), colgrp bc = tid&15 (4 cols)
  const int p2 = tid >> 4;
  const int bc = tid & 15;
  const float* Wb = Wd + (size_t)e * ED * HD + (size_t)(2 * p2) * HD + ntile * 64 + bc * 4;

  f32x4 acc[2][4] = {};
  fv4 b0, b1;

  if (tid < 256) {
    b0 = ldnt4(Wb);
    b1 = ldnt4(Wb + HD);
  }
  async16(agp0, Alds[0] + aofs);
  async16(agp1, Alds[0] + aofs + 512);
  if (tid < 256) {
    u32x4 pkv;
    pkv[0] = pk2(b0[0], b1[0]); pkv[1] = pk2(b0[1], b1[1]);
    pkv[2] = pk2(b0[2], b1[2]); pkv[3] = pk2(b0[3], b1[3]);
    *(u32x4*)(Blds[0] + p2 * BSTG2 + bc * 4) = pkv;
  }
  __syncthreads();

  for (int ks = 0; ks < 32; ++ks) {
    const int cur = ks & 1, nxt = cur ^ 1;
    const bool more = (ks + 1) < 32;
    if (more) {
      if (tid < 256) {
        const float* bp = Wb + (size_t)(ks + 1) * 32 * HD;
        b0 = ldnt4(bp);
        b1 = ldnt4(bp + HD);
      }
      async16(agp0 + (ks + 1) * 32, Alds[nxt] + aofs);
      async16(agp1 + (ks + 1) * 32, Alds[nxt] + aofs + 512);
    }
    short8 af[2], bfr[4];
#pragma unroll
    for (int mi = 0; mi < 2; ++mi)
      af[mi] = *(const short8*)(Alds[cur] + (wv * 32 + mi * 16 + fr) * 32 + q * 8);
#pragma unroll
    for (int ni = 0; ni < 4; ++ni) {
      const unsigned int* p = Blds[cur] + (q * 4) * BSTG2 + ni * 16 + fr;
      union { unsigned int u[4]; short8 s; } uu;
      uu.u[0] = p[0]; uu.u[1] = p[BSTG2]; uu.u[2] = p[2 * BSTG2]; uu.u[3] = p[3 * BSTG2];
      bfr[ni] = uu.s;
    }
#pragma unroll
    for (int mi = 0; mi < 2; ++mi)
#pragma unroll
      for (int ni = 0; ni < 4; ++ni)
        acc[mi][ni] = __builtin_amdgcn_mfma_f32_16x16x32_bf16(af[mi], bfr[ni], acc[mi][ni], 0, 0, 0);
    if (more && tid < 256) {
      u32x4 pkv;
      pkv[0] = pk2(b0[0], b1[0]); pkv[1] = pk2(b0[1], b1[1]);
      pkv[2] = pk2(b0[2], b1[2]); pkv[3] = pk2(b0[3], b1[3]);
      *(u32x4*)(Blds[nxt] + p2 * BSTG2 + bc * 4) = pkv;
    }
    __syncthreads();
  }

  // epilogue: weighted atomic accumulation into out (bd already pre-mixed by router)
#pragma unroll
  for (int mi = 0; mi < 2; ++mi) {
#pragma unroll
    for (int r = 0; r < 4; ++r) {
      const int srow = wv * 32 + mi * 16 + q * 4 + r;
      if ((mtile * 256 + srow) < Ne) {
        const int gsl = base + srow;
        const int tok = gtok[gsl];
        const float wt = gwt[gsl];
        float* op = out + (size_t)tok * HD + ntile * 64;
#pragma unroll
        for (int ni = 0; ni < 4; ++ni) {
          const int col = ni * 16 + fr;
          atomicAdd(op + col, wt * acc[mi][ni][r]);
        }
      }
    }
  }
}

extern "C" void kernel_launch(void* const* d_in, const int* in_sizes, int n_in,
                              void* d_out, int out_size, void* d_ws, size_t ws_size,
                              hipStream_t stream) {
  const float* x   = (const float*)d_in[0];
  const float* Wg  = (const float*)d_in[1];
  const float* bg  = (const float*)d_in[2];
  const float* Wgu = (const float*)d_in[3];
  const float* bgu = (const float*)d_in[4];
  const float* Wd  = (const float*)d_in[5];
  const float* bd  = (const float*)d_in[6];
  float* out = (float*)d_out;

  int* cnt = (int*)d_ws;                    // 16
  int* off = cnt + 16;                      // 16
  int* e01 = off + 16;                      // 1024
  float* w0f = (float*)(e01 + NT);          // 1024
  float* w1f = w0f + NT;                    // 1024
  int* gtok = (int*)(w1f + NT);             // GROWS
  float* gwt = (float*)(gtok + GROWS);      // GROWS
  unsigned short* Xbf = (unsigned short*)(gwt + GROWS);        // NT*HD bf16
  unsigned short* Gact = Xbf + (size_t)NT * HD;                // GROWS*ED bf16

  k_router<<<NT, 64, 0, stream>>>(x, Wg, bg, bd, e01, w0f, w1f, Xbf, out);
  k_scan<<<1, NT, 0, stream>>>(e01, w0f, w1f, cnt, off, gtok, gwt);
  k_gemm1<<<dim3(16, 2, NEXPERT), 512, 0, stream>>>(Xbf, Wgu, bgu, cnt, off, gtok, Gact);
  k_gemm2<<<dim3(16, 2, NEXPERT), 512, 0, stream>>>(Gact, Wd, cnt, off, gtok, gwt, out);
}

// Round 4
// 330.790 us; speedup vs baseline: 1.0383x; 1.0048x over previous
//
#include <hip/hip_runtime.h>
#include <hip/hip_bf16.h>

#define NT 1024     // tokens (B*S)
#define HD 1024     // hidden
#define ED 1024     // expert inner dim
#define F2D 2048    // 2*E (interleaved gate/up)
#define NEXPERT 16
#define GROWS 2304  // compacted rows (2048) + tile slack (gemm2 reads up to base+255 <= 2303)
#define ALPHA_C 1.702f
#define LIMIT_C 7.0f

typedef float f32x4 __attribute__((ext_vector_type(4)));
typedef float fv4 __attribute__((ext_vector_type(4)));
typedef short short8 __attribute__((ext_vector_type(8)));
typedef unsigned int u32x4 __attribute__((ext_vector_type(4)));

__device__ __forceinline__ unsigned short f2bf(float x) {
  union { float f; unsigned int u; } v; v.f = x;
  unsigned int r = v.u + 0x7FFFu + ((v.u >> 16) & 1u);
  return (unsigned short)(r >> 16);
}
__device__ __forceinline__ unsigned int pk2(float lo, float hi) {
  return (unsigned int)f2bf(lo) | ((unsigned int)f2bf(hi) << 16);
}
// non-temporal float4 load (weights: stream, don't cache)
__device__ __forceinline__ fv4 ldnt4(const float* p) {
  return __builtin_nontemporal_load((const fv4*)p);
}
// async global->LDS, 16B per lane; LDS dest = wave-uniform base + lane*16
__device__ __forceinline__ void async16(const void* g, void* l) {
  __builtin_amdgcn_global_load_lds((const __attribute__((address_space(1))) void*)g,
                                   (__attribute__((address_space(3))) void*)l, 16, 0, 0);
}

// ---------------- router: 4 waves/token; partial logits per wave, LDS reduce, redundant top-2 ----------------
__global__ __launch_bounds__(256) void k_router(const float* __restrict__ x,
                                                const float* __restrict__ Wg,
                                                const float* __restrict__ bg,
                                                const float* __restrict__ bd,
                                                int* __restrict__ e01,
                                                float* __restrict__ w0f,
                                                float* __restrict__ w1f,
                                                unsigned short* __restrict__ Xbf,
                                                float* __restrict__ out) {
  const int t = blockIdx.x;
  const int tid = threadIdx.x;     // 0..255
  const int w = tid >> 6;          // wave 0..3 (quarter of HD)
  const int l = tid & 63;
  const float4* x4 = (const float4*)(x + (size_t)t * HD);
  // bf16 conversion: one float4 per thread
  {
    float4 v = x4[tid];
    unsigned int* dst = (unsigned int*)(Xbf + (size_t)t * HD + tid * 4);
    dst[0] = pk2(v.x, v.y); dst[1] = pk2(v.z, v.w);
  }
  // partial logits: expert e = l&15, sub-chunk qq = l>>4; wave w covers float4 idx w*64..w*64+63
  const int e = l & 15, qq = l >> 4;
  const float4* wg4 = (const float4*)(Wg + (size_t)e * HD);
  float s = 0.f;
#pragma unroll 4
  for (int j = 0; j < 16; ++j) {
    const int idx = w * 64 + qq + 4 * j;
    float4 a = x4[idx], b = wg4[idx];
    s += a.x * b.x + a.y * b.y + a.z * b.z + a.w * b.w;
  }
  s += __shfl_xor(s, 16);
  s += __shfl_xor(s, 32);          // lanes 0..15 hold quarter-partial for expert e
  __shared__ float slog[4][16];
  if (l < 16) slog[w][e] = s;
  __syncthreads();
  // all threads: full logits + top2 (redundant, deterministic)
  float v0 = -1e30f, v1 = -1e30f; int i0 = 0, i1 = 0;
  for (int k2 = 0; k2 < 16; ++k2) {
    float lv = slog[0][k2] + slog[1][k2] + slog[2][k2] + slog[3][k2] + bg[k2];
    if (lv > v0) { v1 = v0; i1 = i0; v0 = lv; i0 = k2; }
    else if (lv > v1) { v1 = lv; i1 = k2; }
  }
  const float w0 = 1.f / (1.f + __expf(v1 - v0));
  const float w1 = 1.f - w0;
  if (tid == 0) {
    e01[t] = i0 | (i1 << 8);
    w0f[t] = w0;
    w1f[t] = w1;
  }
  // bd premix: one float4 per thread
  const float4* bd0 = (const float4*)(bd + (size_t)i0 * HD);
  const float4* bd1 = (const float4*)(bd + (size_t)i1 * HD);
  float4 a = bd0[tid], b = bd1[tid];
  float4 r;
  r.x = w0 * a.x + w1 * b.x;
  r.y = w0 * a.y + w1 * b.y;
  r.z = w0 * a.z + w1 * b.z;
  r.w = w0 * a.w + w1 * b.w;
  ((float4*)(out + (size_t)t * HD))[tid] = r;
}

// ---------------- scan: counts, offsets, placement (one block) ----------------
__global__ __launch_bounds__(1024) void k_scan(const int* __restrict__ e01,
                                               const float* __restrict__ w0f,
                                               const float* __restrict__ w1f,
                                               int* __restrict__ cnt,
                                               int* __restrict__ off,
                                               int* __restrict__ gtok,
                                               float* __restrict__ gwt) {
  __shared__ int scnt[NEXPERT];
  __shared__ int soff[NEXPERT];
  __shared__ int scur[NEXPERT];
  const int t = threadIdx.x;
  if (t < NEXPERT) { scnt[t] = 0; scur[t] = 0; }
  __syncthreads();
  const int p = e01[t];
  const int e0 = p & 255, e1 = p >> 8;
  atomicAdd(&scnt[e0], 1);
  atomicAdd(&scnt[e1], 1);
  __syncthreads();
  if (t == 0) {
    int a = 0;
    for (int e = 0; e < NEXPERT; ++e) { soff[e] = a; off[e] = a; cnt[e] = scnt[e]; a += scnt[e]; }
  }
  __syncthreads();
  int s0 = atomicAdd(&scur[e0], 1);
  gtok[soff[e0] + s0] = t; gwt[soff[e0] + s0] = w0f[t];
  int s1 = atomicAdd(&scur[e1], 1);
  gtok[soff[e1] + s1] = t; gwt[soff[e1] + s1] = w1f[t];
}

// ---------------- GEMM1: block 256M x 128N, 512 thr (8 waves 4mx2n), BK=32, dbuf, weights read ONCE ----------------
// grid (16 ntiles, 2 mtiles, 16 experts); Wgu[e] is [K=1024][N=2048]
#define BSTG1 132   // Blds row stride in dwords (128 + 4 pad)
__global__ __launch_bounds__(512, 1) void k_gemm1(const unsigned short* __restrict__ Xbf,
                                                  const float* __restrict__ Wgu,
                                                  const float* __restrict__ bgu,
                                                  const int* __restrict__ cnt,
                                                  const int* __restrict__ off,
                                                  const int* __restrict__ gtok,
                                                  unsigned short* __restrict__ Gact) {
  const int e = blockIdx.z;
  const int Ne = cnt[e];
  const int mtile = blockIdx.y;
  if (mtile * 256 >= Ne) return;
  const int ntile = blockIdx.x;
  const int tid = threadIdx.x;          // 0..511
  const int lane = tid & 63;
  const int wv = tid >> 6;              // 0..7
  const int wm = wv >> 1;               // 0..3  (M 64-slice)
  const int wn = wv & 1;                // 0..1  (N 64-slice)
  const int q = lane >> 4;
  const int fr = lane & 15;
  const int base = off[e] + mtile * 256;

  __shared__ unsigned short Alds[2][256 * 32];   // [buf][row*32 + k]  (64B rows)  32 KB
  __shared__ unsigned int Blds[2][16 * BSTG1];   // [buf][kpair*BSTG1 + n]        ~17 KB

  // A staging: wave wv stages rows wv*32 + (lane>>2) and +16; chunk = lane&3
  const int ar0 = wv * 32 + (lane >> 2);
  const int ar1 = ar0 + 16;
  const int ags0 = base + (((mtile * 256 + ar0) < Ne) ? ar0 : 0);
  const int ags1 = base + (((mtile * 256 + ar1) < Ne) ? ar1 : 0);
  const unsigned short* agp0 = Xbf + (size_t)gtok[ags0] * HD + (lane & 3) * 8;
  const unsigned short* agp1 = Xbf + (size_t)gtok[ags1] * HD + (lane & 3) * 8;
  const int aofs = wv * 1024;  // shorts: 32 rows * 32 shorts

  // B staging: thread -> kpair p2 = tid>>5 (0..15), colgrp bc = tid&31 (4 cols each)
  const int p2 = tid >> 5;
  const int bc = tid & 31;
  const float* Wb = Wgu + (size_t)e * HD * F2D + (size_t)(2 * p2) * F2D + ntile * 128 + bc * 4;

  f32x4 acc[4][4] = {};
  fv4 b0, b1;

  // prologue: stage tile 0
  b0 = ldnt4(Wb);
  b1 = ldnt4(Wb + F2D);
  async16(agp0, Alds[0] + aofs);
  async16(agp1, Alds[0] + aofs + 512);
  {
    u32x4 pkv;
    pkv[0] = pk2(b0[0], b1[0]); pkv[1] = pk2(b0[1], b1[1]);
    pkv[2] = pk2(b0[2], b1[2]); pkv[3] = pk2(b0[3], b1[3]);
    *(u32x4*)(Blds[0] + p2 * BSTG1 + bc * 4) = pkv;
  }
  __syncthreads();

  for (int ks = 0; ks < 32; ++ks) {
    const int cur = ks & 1, nxt = cur ^ 1;
    const bool more = (ks + 1) < 32;
    if (more) {
      const float* bp = Wb + (size_t)(ks + 1) * 32 * F2D;
      b0 = ldnt4(bp);
      b1 = ldnt4(bp + F2D);
      async16(agp0 + (ks + 1) * 32, Alds[nxt] + aofs);
      async16(agp1 + (ks + 1) * 32, Alds[nxt] + aofs + 512);
    }
    short8 af[4], bfr[4];
#pragma unroll
    for (int mi = 0; mi < 4; ++mi)
      af[mi] = *(const short8*)(Alds[cur] + (wm * 64 + mi * 16 + fr) * 32 + q * 8);
#pragma unroll
    for (int ni = 0; ni < 4; ++ni) {
      const unsigned int* p = Blds[cur] + (q * 4) * BSTG1 + wn * 64 + ni * 16 + fr;
      union { unsigned int u[4]; short8 s; } uu;
      uu.u[0] = p[0]; uu.u[1] = p[BSTG1]; uu.u[2] = p[2 * BSTG1]; uu.u[3] = p[3 * BSTG1];
      bfr[ni] = uu.s;
    }
#pragma unroll
    for (int mi = 0; mi < 4; ++mi)
#pragma unroll
      for (int ni = 0; ni < 4; ++ni)
        acc[mi][ni] = __builtin_amdgcn_mfma_f32_16x16x32_bf16(af[mi], bfr[ni], acc[mi][ni], 0, 0, 0);
    if (more) {
      u32x4 pkv;
      pkv[0] = pk2(b0[0], b1[0]); pkv[1] = pk2(b0[1], b1[1]);
      pkv[2] = pk2(b0[2], b1[2]); pkv[3] = pk2(b0[3], b1[3]);
      *(u32x4*)(Blds[nxt] + p2 * BSTG1 + bc * 4) = pkv;
    }
    __syncthreads();
  }

  // epilogue: +bgu, de-interleave gate/up via lane-pair shuffle, activation, store bf16
  const float* bguE = bgu + (size_t)e * F2D + ntile * 128;
#pragma unroll
  for (int mi = 0; mi < 4; ++mi) {
#pragma unroll
    for (int ni = 0; ni < 4; ++ni) {
      const int coll = wn * 64 + ni * 16 + fr;
      const float bias = bguE[coll];
#pragma unroll
      for (int r = 0; r < 4; ++r) {
        const int srow = wm * 64 + mi * 16 + q * 4 + r;
        float v = acc[mi][ni][r] + bias;
        float pv = __shfl_xor(v, 1);
        float gate = (lane & 1) ? pv : v;   // even f2-cols are gate, odd are up
        float up   = (lane & 1) ? v : pv;
        gate = fminf(gate, LIMIT_C);
        up = fminf(fmaxf(up, -LIMIT_C), LIMIT_C);
        float glu = gate / (1.f + __expf(-ALPHA_C * gate));
        float val = (up + 1.f) * glu;
        if (!(lane & 1) && (mtile * 256 + srow) < Ne)
          Gact[(size_t)(base + srow) * ED + ((ntile * 128 + coll) >> 1)] = f2bf(val);
      }
    }
  }
}

// ---------------- GEMM2: block 256M x 64N, 512 thr (8 waves, M-split 32 rows/wave), BK=32, dbuf ----------------
// B in LDS TRANSPOSED [col][kpair] (stride 20 dwords) so a B-fragment = one ds_read_b128.
// In-register 4x4 col/kpair transpose via DPP quad_perm before LDS write (VALU-only).
// grid (16 ntiles, 2 mtiles, 16 experts); Wd[e] is [K=1024][N=1024]; atomic epilogue.
#define BSTG2T 20   // transposed B row stride in dwords (16 kpairs + 4 pad; 80B keeps 16B alignment)
__global__ __launch_bounds__(512, 2) void k_gemm2(const unsigned short* __restrict__ Gact,
                                                  const float* __restrict__ Wd,
                                                  const int* __restrict__ cnt,
                                                  const int* __restrict__ off,
                                                  const int* __restrict__ gtok,
                                                  const float* __restrict__ gwt,
                                                  float* __restrict__ out) {
  const int e = blockIdx.z;
  const int Ne = cnt[e];
  const int mtile = blockIdx.y;
  if (mtile * 256 >= Ne) return;
  const int ntile = blockIdx.x;
  const int tid = threadIdx.x;          // 0..511
  const int lane = tid & 63;
  const int wv = tid >> 6;              // 0..7 (M 32-slice; N full 64)
  const int q = lane >> 4;
  const int fr = lane & 15;
  const int base = off[e] + mtile * 256;

  __shared__ unsigned short Alds[2][256 * 32];     // 32 KB
  __shared__ unsigned int Blds[2][64 * BSTG2T];    // transposed B, ~10.2 KB

  // A staging: wave wv stages rows wv*32 + (lane>>2) and +16; chunk = lane&3
  // rows base+0..255 < GROWS: safe
  const int ar0 = wv * 32 + (lane >> 2);
  const unsigned short* agp0 = Gact + (size_t)(base + ar0) * ED + (lane & 3) * 8;
  const unsigned short* agp1 = agp0 + (size_t)16 * ED;
  const int aofs = wv * 1024;  // shorts: 32 rows * 32 shorts

  // B staging (waves 0..3): quad-based mapping. sub = lane&3, g4 = lane>>2.
  // kpair = wave*4 + sub (0..15); cols g4*4..g4*4+3. After quad transpose each lane
  // writes b128 = col (lane) x kpairs wave*4..+3 at Blds[col*20 + wave*4].
  const int sub = lane & 3;
  const float* Wb = Wd + (size_t)e * ED * HD + (size_t)(2 * (wv * 4 + sub)) * HD + ntile * 64 + (lane >> 2) * 4;

  f32x4 acc[2][4] = {};
  fv4 b0, b1;

#define B2_TRANSPOSE_STORE(BUF)                                                         \
  {                                                                                     \
    unsigned int w0p = pk2(b0[0], b1[0]);                                               \
    unsigned int w1p = pk2(b0[1], b1[1]);                                               \
    unsigned int w2p = pk2(b0[2], b1[2]);                                               \
    unsigned int w3p = pk2(b0[3], b1[3]);                                               \
    unsigned int X0 = sub == 0 ? w0p : sub == 1 ? w1p : sub == 2 ? w2p : w3p;           \
    unsigned int X1 = sub == 0 ? w1p : sub == 1 ? w0p : sub == 2 ? w3p : w2p;           \
    unsigned int X2 = sub == 0 ? w2p : sub == 1 ? w3p : sub == 2 ? w0p : w1p;           \
    unsigned int X3 = sub == 0 ? w3p : sub == 1 ? w2p : sub == 2 ? w1p : w0p;           \
    unsigned int r0 = X0;                                                               \
    unsigned int r1 = (unsigned int)__builtin_amdgcn_update_dpp((int)X1, (int)X1, 0xB1, 0xF, 0xF, 0); \
    unsigned int r2 = (unsigned int)__builtin_amdgcn_update_dpp((int)X2, (int)X2, 0x4E, 0xF, 0xF, 0); \
    unsigned int r3 = (unsigned int)__builtin_amdgcn_update_dpp((int)X3, (int)X3, 0x1B, 0xF, 0xF, 0); \
    u32x4 tt;                                                                           \
    tt[0] = sub == 0 ? r0 : sub == 1 ? r1 : sub == 2 ? r2 : r3;                         \
    tt[1] = sub == 0 ? r1 : sub == 1 ? r0 : sub == 2 ? r3 : r2;                         \
    tt[2] = sub == 0 ? r2 : sub == 1 ? r3 : sub == 2 ? r0 : r1;                         \
    tt[3] = sub == 0 ? r3 : sub == 1 ? r2 : sub == 2 ? r1 : r0;                         \
    *(u32x4*)(Blds[BUF] + lane * BSTG2T + wv * 4) = tt;                                 \
  }

  if (tid < 256) {
    b0 = ldnt4(Wb);
    b1 = ldnt4(Wb + HD);
  }
  async16(agp0, Alds[0] + aofs);
  async16(agp1, Alds[0] + aofs + 512);
  if (tid < 256) B2_TRANSPOSE_STORE(0)
  __syncthreads();

  for (int ks = 0; ks < 32; ++ks) {
    const int cur = ks & 1, nxt = cur ^ 1;
    const bool more = (ks + 1) < 32;
    if (more) {
      if (tid < 256) {
        const float* bp = Wb + (size_t)(ks + 1) * 32 * HD;
        b0 = ldnt4(bp);
        b1 = ldnt4(bp + HD);
      }
      async16(agp0 + (ks + 1) * 32, Alds[nxt] + aofs);
      async16(agp1 + (ks + 1) * 32, Alds[nxt] + aofs + 512);
    }
    short8 af[2], bfr[4];
#pragma unroll
    for (int mi = 0; mi < 2; ++mi)
      af[mi] = *(const short8*)(Alds[cur] + (wv * 32 + mi * 16 + fr) * 32 + q * 8);
#pragma unroll
    for (int ni = 0; ni < 4; ++ni)
      bfr[ni] = *(const short8*)(Blds[cur] + (ni * 16 + fr) * BSTG2T + q * 4);
#pragma unroll
    for (int mi = 0; mi < 2; ++mi)
#pragma unroll
      for (int ni = 0; ni < 4; ++ni)
        acc[mi][ni] = __builtin_amdgcn_mfma_f32_16x16x32_bf16(af[mi], bfr[ni], acc[mi][ni], 0, 0, 0);
    if (more && tid < 256) B2_TRANSPOSE_STORE(nxt)
    __syncthreads();
  }

  // epilogue: weighted atomic accumulation into out (bd already pre-mixed by router)
#pragma unroll
  for (int mi = 0; mi < 2; ++mi) {
#pragma unroll
    for (int r = 0; r < 4; ++r) {
      const int srow = wv * 32 + mi * 16 + q * 4 + r;
      if ((mtile * 256 + srow) < Ne) {
        const int gsl = base + srow;
        const int tok = gtok[gsl];
        const float wt = gwt[gsl];
        float* op = out + (size_t)tok * HD + ntile * 64;
#pragma unroll
        for (int ni = 0; ni < 4; ++ni) {
          const int col = ni * 16 + fr;
          atomicAdd(op + col, wt * acc[mi][ni][r]);
        }
      }
    }
  }
}

extern "C" void kernel_launch(void* const* d_in, const int* in_sizes, int n_in,
                              void* d_out, int out_size, void* d_ws, size_t ws_size,
                              hipStream_t stream) {
  const float* x   = (const float*)d_in[0];
  const float* Wg  = (const float*)d_in[1];
  const float* bg  = (const float*)d_in[2];
  const float* Wgu = (const float*)d_in[3];
  const float* bgu = (const float*)d_in[4];
  const float* Wd  = (const float*)d_in[5];
  const float* bd  = (const float*)d_in[6];
  float* out = (float*)d_out;

  int* cnt = (int*)d_ws;                    // 16
  int* off = cnt + 16;                      // 16
  int* e01 = off + 16;                      // 1024
  float* w0f = (float*)(e01 + NT);          // 1024
  float* w1f = w0f + NT;                    // 1024
  int* gtok = (int*)(w1f + NT);             // GROWS
  float* gwt = (float*)(gtok + GROWS);      // GROWS
  unsigned short* Xbf = (unsigned short*)(gwt + GROWS);        // NT*HD bf16
  unsigned short* Gact = Xbf + (size_t)NT * HD;                // GROWS*ED bf16

  k_router<<<NT, 256, 0, stream>>>(x, Wg, bg, bd, e01, w0f, w1f, Xbf, out);
  k_scan<<<1, NT, 0, stream>>>(e01, w0f, w1f, cnt, off, gtok, gwt);
  k_gemm1<<<dim3(16, 2, NEXPERT), 512, 0, stream>>>(Xbf, Wgu, bgu, cnt, off, gtok, Gact);
  k_gemm2<<<dim3(16, 2, NEXPERT), 512, 0, stream>>>(Gact, Wd, cnt, off, gtok, gwt, out);
}